// Round 4
// baseline (191.082 us; speedup 1.0000x reference)
//
#include <hip/hip_runtime.h>
#include <hip/hip_bf16.h>

typedef unsigned short u16;
typedef unsigned int u32;

#define N_ 256
#define C_ 128
#define H_ 4
#define DH_ 32
#define R_ (N_*N_)

static constexpr float KEY_SCALE_ = 0.17677669529663687f; // 32^-0.5

typedef __attribute__((ext_vector_type(8))) short bf16x8;
typedef __attribute__((ext_vector_type(4))) float f32x4;

__device__ __forceinline__ float bf2f(u16 b){ return __uint_as_float(((u32)b)<<16); }
__device__ __forceinline__ u16 f2bf(float f){
  u32 u = __float_as_uint(f);
  u += 0x7FFFu + ((u>>16)&1u);   // round-to-nearest-even
  return (u16)(u>>16);
}

// ---------------- weight pre-conversion: f32 -> bf16 (KEY_SCALE folded) ----
__global__ __launch_bounds__(256) void wconv_kernel(
    const float* __restrict__ wq, const float* __restrict__ wk,
    const float* __restrict__ wv, const float* __restrict__ wg,
    u16* __restrict__ wtb)
{
  int id = blockIdx.x*256 + threadIdx.x;     // 16384 ids x 4 elems
  int m = id >> 12;
  int e = (id & 4095)*4;
  const float* src = (m==0) ? wq : (m==1) ? wk : (m==2) ? wv : wg;
  const float4 v = *(const float4*)(src + e);
  const float s = (m==0) ? KEY_SCALE_ : 1.f;
  ushort4 o;
  o.x = f2bf(v.x*s); o.y = f2bf(v.y*s); o.z = f2bf(v.z*s); o.w = f2bf(v.w*s);
  *(ushort4*)(wtb + m*16384 + e) = o;
}

// ---------------- fused input projections (MFMA) ---------------------------
#define XSTR 136
__global__ __launch_bounds__(256, 2) void proj_kernel(
    const float* __restrict__ qd, const float* __restrict__ md,
    const u16* __restrict__ wtb, const float* __restrict__ bg,
    u16* __restrict__ qb, u16* __restrict__ kb,
    u16* __restrict__ vb, u16* __restrict__ gb)
{
  __shared__ u16 Xs[256*XSTR];   // 69632 B
  const int t = threadIdx.x;
  const int y = blockIdx.y;
  const size_t row0 = (size_t)blockIdx.x * 256;
  const float* X = y ? md : qd;

  #pragma unroll
  for (int p=0;p<16;p++){
    int id = t + p*256;
    int r = id >> 4, c0 = (id & 15)*8;
    const float* s = X + (row0 + r)*C_ + c0;
    float4 a = *(const float4*)s;
    float4 b = *(const float4*)(s+4);
    u16* d = &Xs[r*XSTR + c0];
    d[0]=f2bf(a.x); d[1]=f2bf(a.y); d[2]=f2bf(a.z); d[3]=f2bf(a.w);
    d[4]=f2bf(b.x); d[5]=f2bf(b.y); d[6]=f2bf(b.z); d[7]=f2bf(b.w);
  }

  const int w = t >> 6, l = t & 63, c = l & 15, g = l >> 4;
  const int matSel = w >> 1;
  const int ctBase = (w & 1) * 4;
  const int matIdx = y ? (matSel ? 2 : 1) : (matSel ? 3 : 0);
  u16* dst = y ? (matSel ? vb : kb) : (matSel ? gb : qb);
  const bool doSig = (!y) && matSel;

  bf16x8 bfr[4][4];
  {
    const u16* wb = wtb + matIdx*16384;
    #pragma unroll
    for (int ctj=0;ctj<4;ctj++){
      const u16* rp = wb + ((ctBase+ctj)*16 + c)*C_ + g*8;
      #pragma unroll
      for (int kk=0;kk<4;kk++)
        bfr[ctj][kk] = *(const bf16x8*)(rp + kk*32);
    }
  }
  float bgv[4];
  if (doSig){
    #pragma unroll
    for (int ctj=0;ctj<4;ctj++) bgv[ctj] = bg[(ctBase+ctj)*16 + c];
  }
  __syncthreads();

  for (int mt=0; mt<16; mt++){
    bf16x8 af[4];
    #pragma unroll
    for (int kk=0;kk<4;kk++)
      af[kk] = *(const bf16x8*)&Xs[(mt*16 + c)*XSTR + kk*32 + g*8];
    f32x4 a0 = {0.f,0.f,0.f,0.f}, a1 = {0.f,0.f,0.f,0.f};
    f32x4 a2 = {0.f,0.f,0.f,0.f}, a3 = {0.f,0.f,0.f,0.f};
    #pragma unroll
    for (int kk=0;kk<4;kk++){
      a0 = __builtin_amdgcn_mfma_f32_16x16x32_bf16(af[kk], bfr[0][kk], a0, 0,0,0);
      a1 = __builtin_amdgcn_mfma_f32_16x16x32_bf16(af[kk], bfr[1][kk], a1, 0,0,0);
      a2 = __builtin_amdgcn_mfma_f32_16x16x32_bf16(af[kk], bfr[2][kk], a2, 0,0,0);
      a3 = __builtin_amdgcn_mfma_f32_16x16x32_bf16(af[kk], bfr[3][kk], a3, 0,0,0);
    }
    f32x4 accs[4] = {a0,a1,a2,a3};
    #pragma unroll
    for (int ctj=0;ctj<4;ctj++){
      #pragma unroll
      for (int r=0;r<4;r++){
        float v = accs[ctj][r];
        if (doSig) v = 1.f/(1.f+__expf(-(v + bgv[ctj])));
        dst[(row0 + mt*16 + 4*g + r)*C_ + (ctBase+ctj)*16 + c] = f2bf(v);
      }
    }
  }
}

// ---------------- attention (MFMA): 2048 blocks ----------------------------
// Flat id decode keeps all 8 blocks of one n on the same XCD (id%8 == n%8).
// Each block: one (n, h, q-half); 4 waves x 2 q-tiles of 16 rows.
// Vt rows d-interleaved (row (d&1)*16 + d/2) -> epilogue packs u32.
// P handled in 32-k chunks through ping-pong LDS buffers (stride 36).
#define VSTR 264
__global__ __launch_bounds__(256) void attn_kernel(
    const u16* qb, const u16* __restrict__ kb,
    const u16* __restrict__ vb, const u16* __restrict__ gb,
    const float* __restrict__ bias, const float* __restrict__ nbias,
    u16* wab)
{
  __shared__ u16 Vt[32*VSTR];        // 16896 B
  __shared__ u16 Ps0[4][16][36];     // 4608 B
  __shared__ u16 Ps1[4][16][36];     // 4608 B
  __shared__ float Bs[256];          // 1024 B  => 27136 B total

  const int t   = threadIdx.x;
  const int id  = blockIdx.x;
  const int n   = id & 255;
  const int sub = id >> 8;           // 0..7
  const int h   = sub & 3;
  const int qh  = sub >> 2;          // q-half
  const int w   = t >> 6;
  const int l   = t & 63;
  const int c   = l & 15;
  const int g   = l >> 4;

  // ---- stage V^T (d-interleaved rows) and bias row ----
  {
    const u16* vsrc = vb + ((size_t)n*N_)*C_ + h*DH_;
    for (int idx = t; idx < 1024; idx += 256){
      int k = idx >> 2, ch = idx & 3;
      ushort4 a = *(const ushort4*)(vsrc + (size_t)k*C_ + ch*8);
      ushort4 b = *(const ushort4*)(vsrc + (size_t)k*C_ + ch*8 + 4);
      u16 e[8] = {(u16)a.x,(u16)a.y,(u16)a.z,(u16)a.w,
                  (u16)b.x,(u16)b.y,(u16)b.z,(u16)b.w};
      int d0 = ch*8;
      #pragma unroll
      for (int jj=0;jj<8;jj++){
        int d = d0 + jj;
        int vr = (d&1)*16 + (d>>1);
        Vt[vr*VSTR + k] = e[jj];
      }
    }
    Bs[t] = bias[(size_t)n*N_ + t];
  }
  __syncthreads();

  // ---- hoist K B-frags ----
  bf16x8 kf[16];
  {
    const u16* kbase = kb + ((size_t)(n*N_ + c))*C_ + h*DH_ + g*8;
    #pragma unroll
    for (int kt=0;kt<16;kt++)
      kf[kt] = *(const bf16x8*)(kbase + (size_t)kt*16*C_);
  }

  const float* nbp = nbias + (size_t)h*N_*N_;

  for (int qt=0; qt<2; qt++){
    const int q0 = qh*128 + w*32 + qt*16;

    bf16x8 af = *(const bf16x8*)(qb + ((size_t)(n*N_ + q0 + c))*C_ + h*DH_ + g*8);

    const float* nbrow = nbp + (size_t)(q0 + 4*g)*N_ + c;
    f32x4 acc[16];
    #pragma unroll
    for (int kt=0;kt<16;kt++){
      const float bsv = Bs[kt*16 + c];
      f32x4 ci;
      #pragma unroll
      for (int r=0;r<4;r++) ci[r] = bsv + nbrow[(size_t)r*N_ + kt*16];
      acc[kt] = __builtin_amdgcn_mfma_f32_16x16x32_bf16(af, kf[kt], ci, 0, 0, 0);
    }

    // softmax across k (16 reg tiles x 16 c-lanes)
    float inv[4];
    #pragma unroll
    for (int r=0;r<4;r++){
      float m = acc[0][r];
      #pragma unroll
      for (int kt=1;kt<16;kt++) m = fmaxf(m, acc[kt][r]);
      #pragma unroll
      for (int s=8;s>=1;s>>=1) m = fmaxf(m, __shfl_xor(m, s));
      float sum = 0.f;
      #pragma unroll
      for (int kt=0;kt<16;kt++){
        float p = __expf(acc[kt][r] - m);
        acc[kt][r] = p;
        sum += p;
      }
      #pragma unroll
      for (int s=8;s>=1;s>>=1) sum += __shfl_xor(sum, s);
      inv[r] = 1.f/sum;
    }

    // PV in 32-k chunks: convert chunk -> ping-pong LDS -> 2 MFMAs
    f32x4 o0 = {0.f,0.f,0.f,0.f}, o1 = {0.f,0.f,0.f,0.f};
    #pragma unroll
    for (int s=0;s<8;s++){
      u16 (*Psb)[16][36] = (s&1) ? Ps1 : Ps0;
      #pragma unroll
      for (int r=0;r<4;r++){
        Psb[w][4*g+r][c]      = f2bf(acc[2*s  ][r]);
        Psb[w][4*g+r][16 + c] = f2bf(acc[2*s+1][r]);
      }
      bf16x8 pa = *(const bf16x8*)&Psb[w][c][g*8];
      bf16x8 v0 = *(const bf16x8*)&Vt[(size_t)c*VSTR      + s*32 + g*8];
      bf16x8 v1 = *(const bf16x8*)&Vt[(size_t)(16+c)*VSTR + s*32 + g*8];
      o0 = __builtin_amdgcn_mfma_f32_16x16x32_bf16(pa, v0, o0, 0, 0, 0);
      o1 = __builtin_amdgcn_mfma_f32_16x16x32_bf16(pa, v1, o1, 0, 0, 0);
    }

    // normalize, gate, store (o0 -> d=2c, o1 -> d=2c+1: packed u32)
    #pragma unroll
    for (int r=0;r<4;r++){
      size_t row = (size_t)n*N_ + q0 + 4*g + r;
      u32 g2 = *(const u32*)&gb[row*C_ + h*DH_ + 2*c];
      float g0v = bf2f((u16)(g2 & 0xFFFFu));
      float g1v = bf2f((u16)(g2 >> 16));
      u32 ov = (u32)f2bf(o0[r]*inv[r]*g0v) | ((u32)f2bf(o1[r]*inv[r]*g1v) << 16);
      *(u32*)&wab[row*C_ + h*DH_ + 2*c] = ov;
    }
  }
}

// ---------------- output projection (MFMA) ---------------------------------
#define WSTR 136
__global__ __launch_bounds__(256, 2) void outproj_kernel(
    const u16* __restrict__ wab, const float* __restrict__ wo,
    const float* __restrict__ bo, float* __restrict__ out)
{
  __shared__ u16 Wos[128*WSTR];   // 34816 B
  const int t = threadIdx.x;
  const size_t row0 = (size_t)blockIdx.x * 128;

  #pragma unroll
  for (int p=0;p<8;p++){
    int id = t + p*256;
    int r = id >> 4, c0 = (id & 15)*8;
    const float* s = wo + r*C_ + c0;
    float4 a = *(const float4*)s;
    float4 b = *(const float4*)(s+4);
    u16* d = &Wos[r*WSTR + c0];
    d[0]=f2bf(a.x); d[1]=f2bf(a.y); d[2]=f2bf(a.z); d[3]=f2bf(a.w);
    d[4]=f2bf(b.x); d[5]=f2bf(b.y); d[6]=f2bf(b.z); d[7]=f2bf(b.w);
  }

  const int w = t >> 6, l = t & 63, c = l & 15, g = l >> 4;

  bf16x8 af[2][4];
  #pragma unroll
  for (int mt=0;mt<2;mt++){
    const u16* ap = wab + (row0 + w*32 + mt*16 + c)*C_ + g*8;
    #pragma unroll
    for (int kk=0;kk<4;kk++)
      af[mt][kk] = *(const bf16x8*)(ap + kk*32);
  }
  __syncthreads();

  for (int ct=0;ct<8;ct++){
    bf16x8 bfr[4];
    #pragma unroll
    for (int kk=0;kk<4;kk++)
      bfr[kk] = *(const bf16x8*)&Wos[(ct*16 + c)*WSTR + kk*32 + g*8];
    f32x4 acc0 = {0.f,0.f,0.f,0.f}, acc1 = {0.f,0.f,0.f,0.f};
    #pragma unroll
    for (int kk=0;kk<4;kk++){
      acc0 = __builtin_amdgcn_mfma_f32_16x16x32_bf16(af[0][kk], bfr[kk], acc0, 0,0,0);
      acc1 = __builtin_amdgcn_mfma_f32_16x16x32_bf16(af[1][kk], bfr[kk], acc1, 0,0,0);
    }
    const float bov = bo[ct*16 + c];
    #pragma unroll
    for (int r=0;r<4;r++){
      out[(row0 + w*32 +      4*g + r)*C_ + ct*16 + c] = acc0[r] + bov;
      out[(row0 + w*32 + 16 + 4*g + r)*C_ + ct*16 + c] = acc1[r] + bov;
    }
  }
}

extern "C" void kernel_launch(void* const* d_in, const int* in_sizes, int n_in,
                              void* d_out, int out_size, void* d_ws, size_t ws_size,
                              hipStream_t stream) {
  const float* qd   = (const float*)d_in[0];
  const float* md   = (const float*)d_in[1];
  const float* bias = (const float*)d_in[2];
  const float* nb   = (const float*)d_in[3];
  const float* wq   = (const float*)d_in[4];
  const float* wk   = (const float*)d_in[5];
  const float* wv   = (const float*)d_in[6];
  const float* wo   = (const float*)d_in[7];
  const float* bo   = (const float*)d_in[8];
  const float* wg   = (const float*)d_in[9];
  const float* bg   = (const float*)d_in[10];
  float* out = (float*)d_out;

  char* ws = (char*)d_ws;
  const size_t MB16 = (size_t)16*1024*1024;
  u16* qb  = (u16*)(ws);
  u16* kb  = (u16*)(ws + MB16);
  u16* vb  = (u16*)(ws + 2*MB16);
  u16* gb  = (u16*)(ws + 3*MB16);
  u16* wab = qb;                    // in-place reuse (disjoint row/col slices)
  u16* wtb = (u16*)d_out;           // bf16 weights scratch in d_out head

  wconv_kernel<<<64, 256, 0, stream>>>(wq, wk, wv, wg, wtb);
  proj_kernel<<<dim3(256, 2), 256, 0, stream>>>(qd, md, wtb, bg, qb, kb, vb, gb);
  attn_kernel<<<2048, 256, 0, stream>>>(qb, kb, vb, gb, bias, nb, wab);
  outproj_kernel<<<512, 256, 0, stream>>>(wab, wo, bo, out);
}

// Round 5
// 135.579 us; speedup vs baseline: 1.4094x; 1.4094x over previous
//
#include <hip/hip_runtime.h>
#include <hip/hip_bf16.h>

typedef unsigned short u16;
typedef unsigned int u32;

#define N_ 256
#define C_ 128
#define H_ 4
#define DH_ 32
#define R_ (N_*N_)

static constexpr float KEY_SCALE_ = 0.17677669529663687f; // 32^-0.5

typedef __attribute__((ext_vector_type(8))) short bf16x8;
typedef __attribute__((ext_vector_type(4))) float f32x4;

__device__ __forceinline__ float bf2f(u16 b){ return __uint_as_float(((u32)b)<<16); }
__device__ __forceinline__ u16 f2bf(float f){
  __hip_bfloat16 h = __float2bfloat16(f);   // RNE; compiler can pair into v_cvt_pk_bf16_f32
  u16 r; __builtin_memcpy(&r, &h, 2); return r;
}

// ---------------- weight pre-conversion: f32 -> bf16 (KEY_SCALE folded) ----
__global__ __launch_bounds__(256) void wconv_kernel(
    const float* __restrict__ wq, const float* __restrict__ wk,
    const float* __restrict__ wv, const float* __restrict__ wg,
    u16* __restrict__ wtb)
{
  int id = blockIdx.x*256 + threadIdx.x;     // 16384 ids x 4 elems
  int m = id >> 12;
  int e = (id & 4095)*4;
  const float* src = (m==0) ? wq : (m==1) ? wk : (m==2) ? wv : wg;
  const float4 v = *(const float4*)(src + e);
  const float s = (m==0) ? KEY_SCALE_ : 1.f;
  ushort4 o;
  o.x = f2bf(v.x*s); o.y = f2bf(v.y*s); o.z = f2bf(v.z*s); o.w = f2bf(v.w*s);
  *(ushort4*)(wtb + m*16384 + e) = o;
}

// ---------------- fused input projections (MFMA) ---------------------------
#define XSTR 136
__global__ __launch_bounds__(256, 2) void proj_kernel(
    const float* __restrict__ qd, const float* __restrict__ md,
    const u16* __restrict__ wtb, const float* __restrict__ bg,
    u16* __restrict__ qb, u16* __restrict__ kb,
    u16* __restrict__ vb, u16* __restrict__ gb)
{
  __shared__ u16 Xs[256*XSTR];   // 69632 B
  const int t = threadIdx.x;
  const int y = blockIdx.y;
  const size_t row0 = (size_t)blockIdx.x * 256;
  const float* X = y ? md : qd;

  #pragma unroll
  for (int p=0;p<16;p++){
    int id = t + p*256;
    int r = id >> 4, c0 = (id & 15)*8;
    const float* s = X + (row0 + r)*C_ + c0;
    float4 a = *(const float4*)s;
    float4 b = *(const float4*)(s+4);
    u16* d = &Xs[r*XSTR + c0];
    d[0]=f2bf(a.x); d[1]=f2bf(a.y); d[2]=f2bf(a.z); d[3]=f2bf(a.w);
    d[4]=f2bf(b.x); d[5]=f2bf(b.y); d[6]=f2bf(b.z); d[7]=f2bf(b.w);
  }

  const int w = t >> 6, l = t & 63, c = l & 15, g = l >> 4;
  const int matSel = w >> 1;
  const int ctBase = (w & 1) * 4;
  const int matIdx = y ? (matSel ? 2 : 1) : (matSel ? 3 : 0);
  u16* dst = y ? (matSel ? vb : kb) : (matSel ? gb : qb);
  const bool doSig = (!y) && matSel;

  bf16x8 bfr[4][4];
  {
    const u16* wb = wtb + matIdx*16384;
    #pragma unroll
    for (int ctj=0;ctj<4;ctj++){
      const u16* rp = wb + ((ctBase+ctj)*16 + c)*C_ + g*8;
      #pragma unroll
      for (int kk=0;kk<4;kk++)
        bfr[ctj][kk] = *(const bf16x8*)(rp + kk*32);
    }
  }
  float bgv[4];
  if (doSig){
    #pragma unroll
    for (int ctj=0;ctj<4;ctj++) bgv[ctj] = bg[(ctBase+ctj)*16 + c];
  }
  __syncthreads();

  for (int mt=0; mt<16; mt++){
    bf16x8 af[4];
    #pragma unroll
    for (int kk=0;kk<4;kk++)
      af[kk] = *(const bf16x8*)&Xs[(mt*16 + c)*XSTR + kk*32 + g*8];
    f32x4 a0 = {0.f,0.f,0.f,0.f}, a1 = {0.f,0.f,0.f,0.f};
    f32x4 a2 = {0.f,0.f,0.f,0.f}, a3 = {0.f,0.f,0.f,0.f};
    #pragma unroll
    for (int kk=0;kk<4;kk++){
      a0 = __builtin_amdgcn_mfma_f32_16x16x32_bf16(af[kk], bfr[0][kk], a0, 0,0,0);
      a1 = __builtin_amdgcn_mfma_f32_16x16x32_bf16(af[kk], bfr[1][kk], a1, 0,0,0);
      a2 = __builtin_amdgcn_mfma_f32_16x16x32_bf16(af[kk], bfr[2][kk], a2, 0,0,0);
      a3 = __builtin_amdgcn_mfma_f32_16x16x32_bf16(af[kk], bfr[3][kk], a3, 0,0,0);
    }
    f32x4 accs[4] = {a0,a1,a2,a3};
    #pragma unroll
    for (int ctj=0;ctj<4;ctj++){
      #pragma unroll
      for (int r=0;r<4;r++){
        float v = accs[ctj][r];
        if (doSig) v = 1.f/(1.f+__expf(-(v + bgv[ctj])));
        dst[(row0 + mt*16 + 4*g + r)*C_ + (ctBase+ctj)*16 + c] = f2bf(v);
      }
    }
  }
}

// ---------------- attention (MFMA): 1024 blocks ----------------------------
// Flat id: n = id&255, h = id>>8 -> all 4 blocks of an n share an XCD.
// 4 waves x 4 q-tiles of 16 rows. Full-P per-wave buffer (stride 268: writes
// spread all 32 banks 2-way). Vt d-interleaved rows (stride 270) -> packed
// u32 epilogue.
#define VSTR 270
#define PSTR 268
__global__ __launch_bounds__(256) void attn_kernel(
    const u16* qb, const u16* __restrict__ kb,
    const u16* __restrict__ vb, const u16* __restrict__ gb,
    const float* __restrict__ bias, const float* __restrict__ nbias,
    u16* wab)
{
  __shared__ u16 Vt[32*VSTR];        // 17280 B
  __shared__ u16 Ps[4][16][PSTR];    // 34304 B
  __shared__ float Bs[256];          // 1024 B  => 52608 B total (3 blocks/CU)

  const int t  = threadIdx.x;
  const int id = blockIdx.x;
  const int n  = id & 255;
  const int h  = id >> 8;
  const int w  = t >> 6;
  const int l  = t & 63;
  const int c  = l & 15;
  const int g  = l >> 4;

  // ---- stage V^T (d-interleaved rows: vr = (d&1)*16 + d/2) and bias ----
  {
    const u16* vsrc = vb + ((size_t)n*N_)*C_ + h*DH_;
    for (int idx = t; idx < 1024; idx += 256){
      int k = idx >> 2, ch = idx & 3;
      ushort4 a = *(const ushort4*)(vsrc + (size_t)k*C_ + ch*8);
      ushort4 b = *(const ushort4*)(vsrc + (size_t)k*C_ + ch*8 + 4);
      u16 e[8] = {(u16)a.x,(u16)a.y,(u16)a.z,(u16)a.w,
                  (u16)b.x,(u16)b.y,(u16)b.z,(u16)b.w};
      int d0 = ch*8;
      #pragma unroll
      for (int jj=0;jj<8;jj++){
        int d = d0 + jj;
        int vr = (d&1)*16 + (d>>1);
        Vt[vr*VSTR + k] = e[jj];
      }
    }
    Bs[t] = bias[(size_t)n*N_ + t];
  }
  __syncthreads();

  // ---- hoist K B-frags ----
  bf16x8 kf[16];
  {
    const u16* kbase = kb + ((size_t)(n*N_ + c))*C_ + h*DH_ + g*8;
    #pragma unroll
    for (int kt=0;kt<16;kt++)
      kf[kt] = *(const bf16x8*)(kbase + (size_t)kt*16*C_);
  }

  const float* nbp = nbias + (size_t)h*N_*N_;

  for (int qt=0; qt<4; qt++){
    const int q0 = w*64 + qt*16;

    bf16x8 af = *(const bf16x8*)(qb + ((size_t)(n*N_ + q0 + c))*C_ + h*DH_ + g*8);

    const float* nbrow = nbp + (size_t)(q0 + 4*g)*N_ + c;
    f32x4 acc[16];
    #pragma unroll
    for (int kt=0;kt<16;kt++){
      const float bsv = Bs[kt*16 + c];
      f32x4 ci;
      #pragma unroll
      for (int r=0;r<4;r++) ci[r] = bsv + nbrow[(size_t)r*N_ + kt*16];
      acc[kt] = __builtin_amdgcn_mfma_f32_16x16x32_bf16(af, kf[kt], ci, 0, 0, 0);
    }

    // softmax across k: tree max / tree sum + 16-lane-group shuffles
    float inv[4];
    #pragma unroll
    for (int r=0;r<4;r++){
      float mx[8];
      #pragma unroll
      for (int i=0;i<8;i++) mx[i] = fmaxf(acc[2*i][r], acc[2*i+1][r]);
      #pragma unroll
      for (int st=4;st>=1;st>>=1)
        #pragma unroll
        for (int i=0;i<st;i++) mx[i] = fmaxf(mx[i], mx[i+st]);
      float m = mx[0];
      #pragma unroll
      for (int s=8;s>=1;s>>=1) m = fmaxf(m, __shfl_xor(m, s));
      float sm[8];
      #pragma unroll
      for (int i=0;i<8;i++){
        float p0 = __expf(acc[2*i][r] - m);
        float p1 = __expf(acc[2*i+1][r] - m);
        acc[2*i][r] = p0; acc[2*i+1][r] = p1;
        sm[i] = p0 + p1;
      }
      #pragma unroll
      for (int st=4;st>=1;st>>=1)
        #pragma unroll
        for (int i=0;i<st;i++) sm[i] += sm[i+st];
      float sum = sm[0];
      #pragma unroll
      for (int s=8;s>=1;s>>=1) sum += __shfl_xor(sum, s);
      inv[r] = 1.f/sum;
    }

    // write P (paired converts -> v_cvt_pk) to per-wave LDS
    #pragma unroll
    for (int m=0;m<8;m++){
      #pragma unroll
      for (int r=0;r<4;r++){
        Ps[w][4*g+r][32*m + c]      = f2bf(acc[2*m][r]);
        Ps[w][4*g+r][32*m + 16 + c] = f2bf(acc[2*m+1][r]);
      }
    }

    // PV: v0 -> d=2c, v1 -> d=2c+1 (interleaved Vt rows)
    f32x4 o0 = {0.f,0.f,0.f,0.f}, o1 = {0.f,0.f,0.f,0.f};
    #pragma unroll
    for (int s=0;s<8;s++){
      bf16x8 pa = *(const bf16x8*)&Ps[w][c][s*32 + g*8];
      bf16x8 v0 = *(const bf16x8*)&Vt[(size_t)c*VSTR      + s*32 + g*8];
      bf16x8 v1 = *(const bf16x8*)&Vt[(size_t)(16+c)*VSTR + s*32 + g*8];
      o0 = __builtin_amdgcn_mfma_f32_16x16x32_bf16(pa, v0, o0, 0, 0, 0);
      o1 = __builtin_amdgcn_mfma_f32_16x16x32_bf16(pa, v1, o1, 0, 0, 0);
    }

    // normalize, gate, store packed u32 (d=2c, 2c+1)
    #pragma unroll
    for (int r=0;r<4;r++){
      size_t row = (size_t)n*N_ + q0 + 4*g + r;
      u32 g2 = *(const u32*)&gb[row*C_ + h*DH_ + 2*c];
      float g0v = bf2f((u16)(g2 & 0xFFFFu));
      float g1v = bf2f((u16)(g2 >> 16));
      u32 ov = (u32)f2bf(o0[r]*inv[r]*g0v) | ((u32)f2bf(o1[r]*inv[r]*g1v) << 16);
      *(u32*)&wab[row*C_ + h*DH_ + 2*c] = ov;
    }
  }
}

// ---------------- output projection (MFMA) ---------------------------------
#define WSTR 136
__global__ __launch_bounds__(256, 2) void outproj_kernel(
    const u16* __restrict__ wab, const float* __restrict__ wo,
    const float* __restrict__ bo, float* __restrict__ out)
{
  __shared__ u16 Wos[128*WSTR];   // 34816 B
  const int t = threadIdx.x;
  const size_t row0 = (size_t)blockIdx.x * 128;

  #pragma unroll
  for (int p=0;p<8;p++){
    int id = t + p*256;
    int r = id >> 4, c0 = (id & 15)*8;
    const float* s = wo + r*C_ + c0;
    float4 a = *(const float4*)s;
    float4 b = *(const float4*)(s+4);
    u16* d = &Wos[r*WSTR + c0];
    d[0]=f2bf(a.x); d[1]=f2bf(a.y); d[2]=f2bf(a.z); d[3]=f2bf(a.w);
    d[4]=f2bf(b.x); d[5]=f2bf(b.y); d[6]=f2bf(b.z); d[7]=f2bf(b.w);
  }

  const int w = t >> 6, l = t & 63, c = l & 15, g = l >> 4;

  bf16x8 af[2][4];
  #pragma unroll
  for (int mt=0;mt<2;mt++){
    const u16* ap = wab + (row0 + w*32 + mt*16 + c)*C_ + g*8;
    #pragma unroll
    for (int kk=0;kk<4;kk++)
      af[mt][kk] = *(const bf16x8*)(ap + kk*32);
  }
  __syncthreads();

  for (int ct=0;ct<8;ct++){
    bf16x8 bfr[4];
    #pragma unroll
    for (int kk=0;kk<4;kk++)
      bfr[kk] = *(const bf16x8*)&Wos[(ct*16 + c)*WSTR + kk*32 + g*8];
    f32x4 acc0 = {0.f,0.f,0.f,0.f}, acc1 = {0.f,0.f,0.f,0.f};
    #pragma unroll
    for (int kk=0;kk<4;kk++){
      acc0 = __builtin_amdgcn_mfma_f32_16x16x32_bf16(af[0][kk], bfr[kk], acc0, 0,0,0);
      acc1 = __builtin_amdgcn_mfma_f32_16x16x32_bf16(af[1][kk], bfr[kk], acc1, 0,0,0);
    }
    const float bov = bo[ct*16 + c];
    #pragma unroll
    for (int r=0;r<4;r++){
      out[(row0 + w*32 +      4*g + r)*C_ + ct*16 + c] = acc0[r] + bov;
      out[(row0 + w*32 + 16 + 4*g + r)*C_ + ct*16 + c] = acc1[r] + bov;
    }
  }
}

extern "C" void kernel_launch(void* const* d_in, const int* in_sizes, int n_in,
                              void* d_out, int out_size, void* d_ws, size_t ws_size,
                              hipStream_t stream) {
  const float* qd   = (const float*)d_in[0];
  const float* md   = (const float*)d_in[1];
  const float* bias = (const float*)d_in[2];
  const float* nb   = (const float*)d_in[3];
  const float* wq   = (const float*)d_in[4];
  const float* wk   = (const float*)d_in[5];
  const float* wv   = (const float*)d_in[6];
  const float* wo   = (const float*)d_in[7];
  const float* bo   = (const float*)d_in[8];
  const float* wg   = (const float*)d_in[9];
  const float* bg   = (const float*)d_in[10];
  float* out = (float*)d_out;

  char* ws = (char*)d_ws;
  const size_t MB16 = (size_t)16*1024*1024;
  u16* qb  = (u16*)(ws);
  u16* kb  = (u16*)(ws + MB16);
  u16* vb  = (u16*)(ws + 2*MB16);
  u16* gb  = (u16*)(ws + 3*MB16);
  u16* wab = qb;                    // in-place reuse (disjoint row/col slices)
  u16* wtb = (u16*)d_out;           // bf16 weights scratch in d_out head

  wconv_kernel<<<64, 256, 0, stream>>>(wq, wk, wv, wg, wtb);
  proj_kernel<<<dim3(256, 2), 256, 0, stream>>>(qd, md, wtb, bg, qb, kb, vb, gb);
  attn_kernel<<<1024, 256, 0, stream>>>(qb, kb, vb, gb, bias, nb, wab);
  outproj_kernel<<<512, 256, 0, stream>>>(wab, wo, bo, out);
}

// Round 6
// 135.113 us; speedup vs baseline: 1.4142x; 1.0035x over previous
//
#include <hip/hip_runtime.h>
#include <hip/hip_bf16.h>

typedef unsigned short u16;
typedef unsigned int u32;

#define N_ 256
#define C_ 128
#define H_ 4
#define DH_ 32
#define R_ (N_*N_)

static constexpr float KEY_SCALE_ = 0.17677669529663687f; // 32^-0.5

typedef __attribute__((ext_vector_type(8))) short bf16x8;
typedef __attribute__((ext_vector_type(4))) float f32x4;

__device__ __forceinline__ float bf2f(u16 b){ return __uint_as_float(((u32)b)<<16); }
__device__ __forceinline__ u16 f2bf(float f){
  u32 u = __float_as_uint(f);
  u += 0x7FFFu + ((u>>16)&1u);   // round-to-nearest-even
  return (u16)(u>>16);
}
__device__ __forceinline__ u32 pack2bf(float lo, float hi){
  return (u32)f2bf(lo) | ((u32)f2bf(hi) << 16);
}

// ---------------- weight pre-conversion: f32 -> bf16 (KEY_SCALE folded) ----
__global__ __launch_bounds__(256) void wconv_kernel(
    const float* __restrict__ wq, const float* __restrict__ wk,
    const float* __restrict__ wv, const float* __restrict__ wg,
    u16* __restrict__ wtb)
{
  int id = blockIdx.x*256 + threadIdx.x;     // 16384 ids x 4 elems
  int m = id >> 12;
  int e = (id & 4095)*4;
  const float* src = (m==0) ? wq : (m==1) ? wk : (m==2) ? wv : wg;
  const float4 v = *(const float4*)(src + e);
  const float s = (m==0) ? KEY_SCALE_ : 1.f;
  ushort4 o;
  o.x = f2bf(v.x*s); o.y = f2bf(v.y*s); o.z = f2bf(v.z*s); o.w = f2bf(v.w*s);
  *(ushort4*)(wtb + m*16384 + e) = o;
}

// ---------------- nbias transpose: nbT[h][k][q] = nb[h][q][k] --------------
// grid (16, 4): x -> 64x64 tile (q0 = (x&3)*64, k0 = (x>>2)*64), y = h.
__global__ __launch_bounds__(256) void nbtr_kernel(
    const float* __restrict__ nb, float* __restrict__ nbT)
{
  __shared__ float T[64][65];
  const int t = threadIdx.x;
  const int q0 = (blockIdx.x & 3)*64, k0 = (blockIdx.x >> 2)*64;
  const int h = blockIdx.y;
  const float* src = nb + (size_t)h*N_*N_;
  float* dst = nbT + (size_t)h*N_*N_;
  #pragma unroll
  for (int p=0;p<16;p++){
    int id = t + p*256;
    int r = id >> 6, cc = id & 63;
    T[cc][r] = src[(size_t)(q0 + r)*N_ + k0 + cc];
  }
  __syncthreads();
  #pragma unroll
  for (int p=0;p<16;p++){
    int id = t + p*256;
    int r = id >> 6, cc = id & 63;
    dst[(size_t)(k0 + r)*N_ + q0 + cc] = T[r][cc];
  }
}

// ---------------- fused input projections (MFMA) ---------------------------
#define XSTR 136
__global__ __launch_bounds__(256, 2) void proj_kernel(
    const float* __restrict__ qd, const float* __restrict__ md,
    const u16* __restrict__ wtb, const float* __restrict__ bg,
    u16* __restrict__ qb, u16* __restrict__ kb,
    u16* __restrict__ vb, u16* __restrict__ gb)
{
  __shared__ u16 Xs[256*XSTR];   // 69632 B
  const int t = threadIdx.x;
  const int y = blockIdx.y;
  const size_t row0 = (size_t)blockIdx.x * 256;
  const float* X = y ? md : qd;

  #pragma unroll
  for (int p=0;p<16;p++){
    int id = t + p*256;
    int r = id >> 4, c0 = (id & 15)*8;
    const float* s = X + (row0 + r)*C_ + c0;
    float4 a = *(const float4*)s;
    float4 b = *(const float4*)(s+4);
    u16* d = &Xs[r*XSTR + c0];
    d[0]=f2bf(a.x); d[1]=f2bf(a.y); d[2]=f2bf(a.z); d[3]=f2bf(a.w);
    d[4]=f2bf(b.x); d[5]=f2bf(b.y); d[6]=f2bf(b.z); d[7]=f2bf(b.w);
  }

  const int w = t >> 6, l = t & 63, c = l & 15, g = l >> 4;
  const int matSel = w >> 1;
  const int ctBase = (w & 1) * 4;
  const int matIdx = y ? (matSel ? 2 : 1) : (matSel ? 3 : 0);
  u16* dst = y ? (matSel ? vb : kb) : (matSel ? gb : qb);
  const bool doSig = (!y) && matSel;

  bf16x8 bfr[4][4];
  {
    const u16* wb = wtb + matIdx*16384;
    #pragma unroll
    for (int ctj=0;ctj<4;ctj++){
      const u16* rp = wb + ((ctBase+ctj)*16 + c)*C_ + g*8;
      #pragma unroll
      for (int kk=0;kk<4;kk++)
        bfr[ctj][kk] = *(const bf16x8*)(rp + kk*32);
    }
  }
  float bgv[4];
  if (doSig){
    #pragma unroll
    for (int ctj=0;ctj<4;ctj++) bgv[ctj] = bg[(ctBase+ctj)*16 + c];
  }
  __syncthreads();

  for (int mt=0; mt<16; mt++){
    bf16x8 af[4];
    #pragma unroll
    for (int kk=0;kk<4;kk++)
      af[kk] = *(const bf16x8*)&Xs[(mt*16 + c)*XSTR + kk*32 + g*8];
    f32x4 a0 = {0.f,0.f,0.f,0.f}, a1 = {0.f,0.f,0.f,0.f};
    f32x4 a2 = {0.f,0.f,0.f,0.f}, a3 = {0.f,0.f,0.f,0.f};
    #pragma unroll
    for (int kk=0;kk<4;kk++){
      a0 = __builtin_amdgcn_mfma_f32_16x16x32_bf16(af[kk], bfr[0][kk], a0, 0,0,0);
      a1 = __builtin_amdgcn_mfma_f32_16x16x32_bf16(af[kk], bfr[1][kk], a1, 0,0,0);
      a2 = __builtin_amdgcn_mfma_f32_16x16x32_bf16(af[kk], bfr[2][kk], a2, 0,0,0);
      a3 = __builtin_amdgcn_mfma_f32_16x16x32_bf16(af[kk], bfr[3][kk], a3, 0,0,0);
    }
    f32x4 accs[4] = {a0,a1,a2,a3};
    #pragma unroll
    for (int ctj=0;ctj<4;ctj++){
      #pragma unroll
      for (int r=0;r<4;r++){
        float v = accs[ctj][r];
        if (doSig) v = 1.f/(1.f+__expf(-(v + bgv[ctj])));
        dst[(row0 + mt*16 + 4*g + r)*C_ + (ctBase+ctj)*16 + c] = f2bf(v);
      }
    }
  }
}

// ---------------- attention (MFMA): one block per (n, h) -------------------
// Round-3 structure (grid dim3(H,N): id%8 fixes h -> each XCD owns one
// h-plane). Changes vs round 3: (a) C-init reads pre-transposed nbT via
// float4 (16 loads/lane-qt instead of 64); (b) k-permutation sigma
// (sigma(32m+c)=32m+2c, sigma(32m+16+c)=32m+2c+1) applied to BOTH P storage
// and Vt columns -> P writes become 32 packed b32 instead of 64 scalar b16.
#define VSTR 264
__global__ __launch_bounds__(256) void attn_kernel(
    const u16* qb, const u16* __restrict__ kb,
    const u16* __restrict__ vb, const u16* __restrict__ gb,
    const float* __restrict__ bias, const float* __restrict__ nbT,
    u16* wab)
{
  __shared__ u16 Vt[32*VSTR];        // 16896 B
  __shared__ u16 Ps[4][16][VSTR];    // 33792 B
  __shared__ float Bs[256];          // 1024 B  => 51712 B total

  const int t  = threadIdx.x;
  const int h  = blockIdx.x;
  const int n  = blockIdx.y;
  const int w  = t >> 6;
  const int l  = t & 63;
  const int c  = l & 15;
  const int g  = l >> 4;

  // ---- stage V^T (columns sigma-permuted) and bias row ----
  {
    const u16* vsrc = vb + ((size_t)n*N_)*C_ + h*DH_;
    for (int idx = t; idx < 1024; idx += 256){
      int k = idx >> 2, ch = idx & 3;
      int sk = (k & ~31) | ((k & 15) << 1) | ((k >> 4) & 1);   // sigma(k)
      ushort4 a = *(const ushort4*)(vsrc + (size_t)k*C_ + ch*8);
      ushort4 b = *(const ushort4*)(vsrc + (size_t)k*C_ + ch*8 + 4);
      int d0 = ch*8;
      Vt[(d0+0)*VSTR + sk] = a.x;  Vt[(d0+1)*VSTR + sk] = a.y;
      Vt[(d0+2)*VSTR + sk] = a.z;  Vt[(d0+3)*VSTR + sk] = a.w;
      Vt[(d0+4)*VSTR + sk] = b.x;  Vt[(d0+5)*VSTR + sk] = b.y;
      Vt[(d0+6)*VSTR + sk] = b.z;  Vt[(d0+7)*VSTR + sk] = b.w;
    }
    Bs[t] = bias[(size_t)n*N_ + t];
  }
  __syncthreads();

  // ---- hoist K B-frags ----
  bf16x8 kf[16];
  {
    const u16* kbase = kb + ((size_t)(n*N_ + c))*C_ + h*DH_ + g*8;
    #pragma unroll
    for (int kt=0;kt<16;kt++)
      kf[kt] = *(const bf16x8*)(kbase + (size_t)kt*16*C_);
  }

  const float* nbtp = nbT + (size_t)h*N_*N_;

  for (int qt=0; qt<4; qt++){
    const int q0 = w*64 + qt*16;

    bf16x8 af = *(const bf16x8*)(qb + ((size_t)(n*N_ + q0 + c))*C_ + h*DH_ + g*8);

    // QK^T with bias in C; nbT[k][q] -> float4 over the 4 rows r
    f32x4 acc[16];
    #pragma unroll
    for (int kt=0;kt<16;kt++){
      const float bsv = Bs[kt*16 + c];
      const float4 nb4 = *(const float4*)(nbtp + (size_t)(kt*16 + c)*N_ + q0 + 4*g);
      f32x4 ci;
      ci[0] = bsv + nb4.x; ci[1] = bsv + nb4.y;
      ci[2] = bsv + nb4.z; ci[3] = bsv + nb4.w;
      acc[kt] = __builtin_amdgcn_mfma_f32_16x16x32_bf16(af, kf[kt], ci, 0, 0, 0);
    }

    // softmax across k (16 reg tiles x 16 c-lanes)
    float inv[4];
    #pragma unroll
    for (int r=0;r<4;r++){
      float m = acc[0][r];
      #pragma unroll
      for (int kt=1;kt<16;kt++) m = fmaxf(m, acc[kt][r]);
      #pragma unroll
      for (int s=8;s>=1;s>>=1) m = fmaxf(m, __shfl_xor(m, s));
      float sum = 0.f;
      #pragma unroll
      for (int kt=0;kt<16;kt++){
        float p = __expf(acc[kt][r] - m);
        acc[kt][r] = p;
        sum += p;
      }
      #pragma unroll
      for (int s=8;s>=1;s>>=1) sum += __shfl_xor(sum, s);
      inv[r] = 1.f/sum;
    }

    // write P to per-wave LDS: packed u32 at sigma-column 32m+2c
    #pragma unroll
    for (int m=0;m<8;m++){
      #pragma unroll
      for (int r=0;r<4;r++)
        *(u32*)&Ps[w][4*g+r][32*m + 2*c] = pack2bf(acc[2*m][r], acc[2*m+1][r]);
    }

    // PV (k-storage is sigma-ordered on both operands)
    f32x4 o0 = {0.f,0.f,0.f,0.f}, o1 = {0.f,0.f,0.f,0.f};
    #pragma unroll
    for (int s=0;s<8;s++){
      bf16x8 pa = *(const bf16x8*)&Ps[w][c][s*32 + g*8];
      bf16x8 v0 = *(const bf16x8*)&Vt[(size_t)c*VSTR      + s*32 + g*8];
      bf16x8 v1 = *(const bf16x8*)&Vt[(size_t)(16+c)*VSTR + s*32 + g*8];
      o0 = __builtin_amdgcn_mfma_f32_16x16x32_bf16(pa, v0, o0, 0, 0, 0);
      o1 = __builtin_amdgcn_mfma_f32_16x16x32_bf16(pa, v1, o1, 0, 0, 0);
    }

    // normalize, gate, store
    #pragma unroll
    for (int r=0;r<4;r++){
      size_t row = (size_t)n*N_ + q0 + 4*g + r;
      float gv0 = bf2f(gb[row*C_ + h*DH_ + c]);
      float gv1 = bf2f(gb[row*C_ + h*DH_ + 16 + c]);
      wab[row*C_ + h*DH_ + c]      = f2bf(o0[r]*inv[r]*gv0);
      wab[row*C_ + h*DH_ + 16 + c] = f2bf(o1[r]*inv[r]*gv1);
    }
  }
}

// ---------------- output projection (MFMA) ---------------------------------
#define WSTR 136
__global__ __launch_bounds__(256, 2) void outproj_kernel(
    const u16* __restrict__ wab, const float* __restrict__ wo,
    const float* __restrict__ bo, float* __restrict__ out)
{
  __shared__ u16 Wos[128*WSTR];   // 34816 B
  const int t = threadIdx.x;
  const size_t row0 = (size_t)blockIdx.x * 128;

  #pragma unroll
  for (int p=0;p<8;p++){
    int id = t + p*256;
    int r = id >> 4, c0 = (id & 15)*8;
    const float* s = wo + r*C_ + c0;
    float4 a = *(const float4*)s;
    float4 b = *(const float4*)(s+4);
    u16* d = &Wos[r*WSTR + c0];
    d[0]=f2bf(a.x); d[1]=f2bf(a.y); d[2]=f2bf(a.z); d[3]=f2bf(a.w);
    d[4]=f2bf(b.x); d[5]=f2bf(b.y); d[6]=f2bf(b.z); d[7]=f2bf(b.w);
  }

  const int w = t >> 6, l = t & 63, c = l & 15, g = l >> 4;

  bf16x8 af[2][4];
  #pragma unroll
  for (int mt=0;mt<2;mt++){
    const u16* ap = wab + (row0 + w*32 + mt*16 + c)*C_ + g*8;
    #pragma unroll
    for (int kk=0;kk<4;kk++)
      af[mt][kk] = *(const bf16x8*)(ap + kk*32);
  }
  __syncthreads();

  for (int ct=0;ct<8;ct++){
    bf16x8 bfr[4];
    #pragma unroll
    for (int kk=0;kk<4;kk++)
      bfr[kk] = *(const bf16x8*)&Wos[(ct*16 + c)*WSTR + kk*32 + g*8];
    f32x4 acc0 = {0.f,0.f,0.f,0.f}, acc1 = {0.f,0.f,0.f,0.f};
    #pragma unroll
    for (int kk=0;kk<4;kk++){
      acc0 = __builtin_amdgcn_mfma_f32_16x16x32_bf16(af[0][kk], bfr[kk], acc0, 0,0,0);
      acc1 = __builtin_amdgcn_mfma_f32_16x16x32_bf16(af[1][kk], bfr[kk], acc1, 0,0,0);
    }
    const float bov = bo[ct*16 + c];
    #pragma unroll
    for (int r=0;r<4;r++){
      out[(row0 + w*32 +      4*g + r)*C_ + ct*16 + c] = acc0[r] + bov;
      out[(row0 + w*32 + 16 + 4*g + r)*C_ + ct*16 + c] = acc1[r] + bov;
    }
  }
}

extern "C" void kernel_launch(void* const* d_in, const int* in_sizes, int n_in,
                              void* d_out, int out_size, void* d_ws, size_t ws_size,
                              hipStream_t stream) {
  const float* qd   = (const float*)d_in[0];
  const float* md   = (const float*)d_in[1];
  const float* bias = (const float*)d_in[2];
  const float* nb   = (const float*)d_in[3];
  const float* wq   = (const float*)d_in[4];
  const float* wk   = (const float*)d_in[5];
  const float* wv   = (const float*)d_in[6];
  const float* wo   = (const float*)d_in[7];
  const float* bo   = (const float*)d_in[8];
  const float* wg   = (const float*)d_in[9];
  const float* bg   = (const float*)d_in[10];
  float* out = (float*)d_out;

  char* ws = (char*)d_ws;
  const size_t MB16 = (size_t)16*1024*1024;
  u16* qb  = (u16*)(ws);
  u16* kb  = (u16*)(ws + MB16);
  u16* vb  = (u16*)(ws + 2*MB16);
  u16* gb  = (u16*)(ws + 3*MB16);
  u16* wab = qb;                    // in-place reuse (disjoint row/col slices)
  // scratch carved from d_out (32 MB); all consumed before outproj overwrites:
  u16*   wtb = (u16*)d_out;                         // 128 KB bf16 weights
  float* nbT = (float*)((char*)d_out + 131072);     // 1 MB transposed nbias

  wconv_kernel<<<64, 256, 0, stream>>>(wq, wk, wv, wg, wtb);
  nbtr_kernel<<<dim3(16, 4), 256, 0, stream>>>(nb, nbT);
  proj_kernel<<<dim3(256, 2), 256, 0, stream>>>(qd, md, wtb, bg, qb, kb, vb, gb);
  attn_kernel<<<dim3(H_, N_), 256, 0, stream>>>(qb, kb, vb, gb, bias, nbT, wab);
  outproj_kernel<<<512, 256, 0, stream>>>(wab, wo, bo, out);
}